// Round 8
// baseline (1457.503 us; speedup 1.0000x reference)
//
#include <hip/hip_runtime.h>
#include <math.h>

#define BB 512   // batch
#define TT 256   // time steps
#define EE 128   // hidden
#define GG 512   // 4*E gates
#define XROW 257 // T+1

// sigmoid and tanh via one shared exp path: tanh(x) = 2*sigmoid(2x) - 1
__device__ __forceinline__ float sig_(float v) {
    return 1.0f / (1.0f + __expf(-v));
}
__device__ __forceinline__ float tanh2_(float v) {
    return fmaf(2.0f, sig_(2.0f * v), -1.0f);
}

// Thread (rg = t&127, cg = t>>7) owns rows 4rg..4rg+3 x cols 16cg..16cg+15.
// 64 weights in 64 NAMED SCALAR floats, pinned to AGPRs ("+a"): the unified
// gfx950 file gives 64 VGPR (compiler's hard budget) + 64 AGPR = weights
// resident, working set in VGPRs, zero scratch spill.
#define DECL_ROW(R) float w##R##_0,w##R##_1,w##R##_2,w##R##_3,w##R##_4,w##R##_5, \
  w##R##_6,w##R##_7,w##R##_8,w##R##_9,w##R##_10,w##R##_11,w##R##_12,w##R##_13, \
  w##R##_14,w##R##_15
#define DECLW DECL_ROW(0); DECL_ROW(1); DECL_ROW(2); DECL_ROW(3)

#define LOAD_ROW(R, P) do { const float4* _q = (const float4*)(P); \
  float4 _a=_q[0], _b=_q[1], _c=_q[2], _d=_q[3]; \
  w##R##_0=_a.x;  w##R##_1=_a.y;  w##R##_2=_a.z;  w##R##_3=_a.w; \
  w##R##_4=_b.x;  w##R##_5=_b.y;  w##R##_6=_b.z;  w##R##_7=_b.w; \
  w##R##_8=_c.x;  w##R##_9=_c.y;  w##R##_10=_c.z; w##R##_11=_c.w; \
  w##R##_12=_d.x; w##R##_13=_d.y; w##R##_14=_d.z; w##R##_15=_d.w; } while(0)
#define LOADW(P) do { const float* _pp = (P); \
  LOAD_ROW(0, _pp); LOAD_ROW(1, _pp + EE); \
  LOAD_ROW(2, _pp + 2*EE); LOAD_ROW(3, _pp + 3*EE); } while(0)

// AGPR pin: tied scalar "a" constraints (scalar tied operands are the only
// compile-safe form, round 4; "a" = AGPR register class).
#define KEEP_ROW(R) asm volatile("" : \
  "+a"(w##R##_0),"+a"(w##R##_1),"+a"(w##R##_2),"+a"(w##R##_3), \
  "+a"(w##R##_4),"+a"(w##R##_5),"+a"(w##R##_6),"+a"(w##R##_7), \
  "+a"(w##R##_8),"+a"(w##R##_9),"+a"(w##R##_10),"+a"(w##R##_11), \
  "+a"(w##R##_12),"+a"(w##R##_13),"+a"(w##R##_14),"+a"(w##R##_15))
#define KEEPW do { KEEP_ROW(0); KEEP_ROW(1); KEEP_ROW(2); KEEP_ROW(3); } while(0)

#define FMA_ROW(R, A) do { \
  A=fmaf(w##R##_0 , x0.x, A); A=fmaf(w##R##_1 , x0.y, A); \
  A=fmaf(w##R##_2 , x0.z, A); A=fmaf(w##R##_3 , x0.w, A); \
  A=fmaf(w##R##_4 , x1.x, A); A=fmaf(w##R##_5 , x1.y, A); \
  A=fmaf(w##R##_6 , x1.z, A); A=fmaf(w##R##_7 , x1.w, A); \
  A=fmaf(w##R##_8 , x2.x, A); A=fmaf(w##R##_9 , x2.y, A); \
  A=fmaf(w##R##_10, x2.z, A); A=fmaf(w##R##_11, x2.w, A); \
  A=fmaf(w##R##_12, x3.x, A); A=fmaf(w##R##_13, x3.y, A); \
  A=fmaf(w##R##_14, x3.z, A); A=fmaf(w##R##_15, x3.w, A); } while(0)

// dot phase: 4 broadcast ds_read_b128 + 64 FMA + one b128 partial write
#define DOT_PHASE() do { \
  const float4* _hp = (const float4*)(h_lds + 16*cg); \
  float4 x0=_hp[0], x1=_hp[1], x2=_hp[2], x3=_hp[3]; \
  float a0=0.f, a1=0.f, a2=0.f, a3=0.f; \
  FMA_ROW(0,a0); FMA_ROW(1,a1); FMA_ROW(2,a2); FMA_ROW(3,a3); \
  *(float4*)&part[cg*GG + rg*4] = make_float4(a0,a1,a2,a3); \
} while(0)

// psum + nonlinearity: thread q (<128) produces rows 4q..4q+3 (one gate type).
__device__ __forceinline__ void psum_nl(const float* part, float* nlg, int q,
                                        float u, float4 cwih4, float4 cb4) {
    float4 s4 = *(const float4*)&part[4 * q];
    #pragma unroll
    for (int c = 1; c < 8; ++c) {
        float4 p4 = *(const float4*)&part[c * GG + 4 * q];
        s4.x += p4.x; s4.y += p4.y; s4.z += p4.z; s4.w += p4.w;
    }
    const bool istanh = (q >= 64) && (q < 96);
    const float sc = istanh ? 2.0f : 1.0f;
    const float cc = istanh ? -1.0f : 0.0f;
    float4 n4;
    n4.x = fmaf(sc, sig_(sc * (s4.x + fmaf(u, cwih4.x, cb4.x))), cc);
    n4.y = fmaf(sc, sig_(sc * (s4.y + fmaf(u, cwih4.y, cb4.y))), cc);
    n4.z = fmaf(sc, sig_(sc * (s4.z + fmaf(u, cwih4.z, cb4.z))), cc);
    n4.w = fmaf(sc, sig_(sc * (s4.w + fmaf(u, cwih4.w, cb4.w))), cc);
    *(float4*)&nlg[4 * q] = n4;
}

// ---------------------------------------------------------------------------
// Encoder
// ---------------------------------------------------------------------------
__global__ __attribute__((amdgpu_flat_work_group_size(1024, 1024),
                          amdgpu_waves_per_eu(4, 4)))
void enc_kernel(const float* __restrict__ x,
                const float* __restrict__ enc_wih,
                const float* __restrict__ enc_whh,
                const float* __restrict__ enc_bias,
                float* __restrict__ hc_ws)
{
    const int t  = threadIdx.x;
    const int rg = t & 127;
    const int cg = t >> 7;
    const int b  = blockIdx.x;

    __shared__ __align__(16) float h_lds[EE];
    __shared__ __align__(16) float part[8 * GG];
    __shared__ __align__(16) float nlg[GG];
    __shared__ float xbuf[2];

    DECLW;
    float c_reg = 0.0f;
    float4 cwih4 = make_float4(0.f,0.f,0.f,0.f);
    float4 cb4   = make_float4(0.f,0.f,0.f,0.f);

    LOADW(enc_whh + (4 * rg) * EE + 16 * cg);
    if (t < EE) {
        cwih4 = *(const float4*)(enc_wih + 4 * t);
        cb4   = *(const float4*)(enc_bias + 4 * t);
        h_lds[t] = 0.0f;
    }
    if (t == 512) xbuf[0] = x[b * XROW + 0];
    __syncthreads();

    for (int s = 0; s < TT; ++s) {
        KEEPW;
        DOT_PHASE();
        __syncthreads();
        if (t < EE) psum_nl(part, nlg, t, xbuf[s & 1], cwih4, cb4);
        if (t == 512 && s + 1 < TT) xbuf[(s + 1) & 1] = x[b * XROW + s + 1];
        __syncthreads();
        if (t < EE) {
            float i_ = nlg[t], f_ = nlg[EE + t], g_ = nlg[2*EE + t], o_ = nlg[3*EE + t];
            c_reg = fmaf(f_, c_reg, i_ * g_);
            h_lds[t] = o_ * tanh2_(c_reg);
        }
        __syncthreads();
    }

    if (t < EE) {
        hc_ws[b * EE + t] = h_lds[t];
        hc_ws[BB * EE + b * EE + t] = c_reg;
    }
}

// ---------------------------------------------------------------------------
// Decoder
// ---------------------------------------------------------------------------
__global__ __attribute__((amdgpu_flat_work_group_size(1024, 1024),
                          amdgpu_waves_per_eu(4, 4)))
void dec_kernel(const float* __restrict__ x,
                const float* __restrict__ dec_wih,
                const float* __restrict__ dec_whh,
                const float* __restrict__ dec_bias,
                const float* __restrict__ lin_w,
                const float* __restrict__ lin_b,
                const float* __restrict__ hc_ws,
                float* __restrict__ out)
{
    const int t  = threadIdx.x;
    const int rg = t & 127;
    const int cg = t >> 7;
    const int b  = blockIdx.x;

    __shared__ __align__(16) float h_lds[EE];
    __shared__ __align__(16) float part[8 * GG];
    __shared__ __align__(16) float nlg[GG];
    __shared__ __align__(16) float out_lds[TT];
    __shared__ float xbuf[2];
    __shared__ float osum[2];

    const int id = (int)x[b * XROW + TT];

    DECLW;
    float c_reg = 0.0f;
    float4 cwih4 = make_float4(0.f,0.f,0.f,0.f);
    float4 cb4   = make_float4(0.f,0.f,0.f,0.f);
    const float lb_v = lin_b[id];
    float wl = 0.0f;

    LOADW(dec_whh + id * GG * EE + (4 * rg) * EE + 16 * cg);
    if (t < EE) {
        cwih4 = *(const float4*)(dec_wih + id * GG + 4 * t);
        cb4   = *(const float4*)(dec_bias + id * GG + 4 * t);
        float hv = hc_ws[b * EE + t];
        h_lds[t] = hv;
        c_reg = hc_ws[BB * EE + b * EE + t];
        wl = lin_w[id * EE + t];
        float p = hv * wl;
        #pragma unroll
        for (int off = 32; off >= 1; off >>= 1) p += __shfl_xor(p, off);
        if ((t & 63) == 0) osum[t >> 6] = p;
    }
    __syncthreads();
    if (t == 512) xbuf[0] = osum[0] + osum[1] + lb_v;   // u0
    __syncthreads();

    for (int s = 0; s < TT; ++s) {
        KEEPW;
        DOT_PHASE();
        __syncthreads();
        if (t < EE) psum_nl(part, nlg, t, xbuf[s & 1], cwih4, cb4);
        // u_{s+1} = rev[s] = x[b][255-s]
        if (t == 512 && s + 1 < TT) xbuf[(s + 1) & 1] = x[b * XROW + (TT - 1 - s)];
        // previous step's output (osum from step s-1, stable this phase)
        if (t == 513 && s > 0) out_lds[TT - s] = osum[0] + osum[1] + lb_v;
        __syncthreads();
        if (t < EE) {
            float i_ = nlg[t], f_ = nlg[EE + t], g_ = nlg[2*EE + t], o_ = nlg[3*EE + t];
            c_reg = fmaf(f_, c_reg, i_ * g_);
            float h_new = o_ * tanh2_(c_reg);
            h_lds[t] = h_new;
            float p = h_new * wl;
            #pragma unroll
            for (int off = 32; off >= 1; off >>= 1) p += __shfl_xor(p, off);
            if ((t & 63) == 0) osum[t >> 6] = p;
        }
        __syncthreads();
    }
    if (t == 512) out_lds[0] = osum[0] + osum[1] + lb_v;  // step 255 -> pos 0
    __syncthreads();

    if (t < 64) *(float4*)(out + b * TT + 4 * t) = ((const float4*)out_lds)[t];
}

extern "C" void kernel_launch(void* const* d_in, const int* in_sizes, int n_in,
                              void* d_out, int out_size, void* d_ws, size_t ws_size,
                              hipStream_t stream) {
    const float* x       = (const float*)d_in[0];
    const float* enc_wih = (const float*)d_in[1];
    const float* enc_whh = (const float*)d_in[2];
    const float* enc_b   = (const float*)d_in[3];
    const float* dec_wih = (const float*)d_in[4];
    const float* dec_whh = (const float*)d_in[5];
    const float* dec_b   = (const float*)d_in[6];
    const float* lin_w   = (const float*)d_in[7];
    const float* lin_b   = (const float*)d_in[8];
    float* out = (float*)d_out;
    float* ws  = (float*)d_ws;  // 2*B*E floats = 512 KB

    hipLaunchKernelGGL(enc_kernel, dim3(BB), dim3(1024), 0, stream,
                       x, enc_wih, enc_whh, enc_b, ws);
    hipLaunchKernelGGL(dec_kernel, dim3(BB), dim3(1024), 0, stream,
                       x, dec_wih, dec_whh, dec_b, lin_w, lin_b, ws, out);
}

// Round 9
// 852.829 us; speedup vs baseline: 1.7090x; 1.7090x over previous
//
#include <hip/hip_runtime.h>
#include <math.h>

#define BB 512   // batch
#define TT 256   // time steps
#define EE 128   // hidden
#define GG 512   // 4*E gate rows
#define XROW 257 // T+1
#define NCHUNK 5 // decoder chunks per id (capacity 80 >> max count ~50)

typedef __attribute__((ext_vector_type(8))) short bf16x8;  // 8 bf16 = 4 VGPRs
typedef __attribute__((ext_vector_type(4))) float f32x4;

__device__ __forceinline__ float sig_(float v){ return 1.0f/(1.0f+__expf(-v)); }
__device__ __forceinline__ float tanh2_(float v){ return fmaf(2.0f, sig_(2.0f*v), -1.0f); }
__device__ __forceinline__ unsigned short bf16_(float f){  // RNE f32->bf16
    unsigned u = __float_as_uint(f);
    return (unsigned short)((u + 0x7fffu + ((u>>16)&1u)) >> 16);
}

// A-frag (16x32 tile of W, row-major 512x128): lane l holds
// W[16rt + (l&15)][32kt + 8*(l>>4) + i], i=0..7  (8 consecutive floats).
__device__ __forceinline__ bf16x8 load_afrag(const float* W, int rt, int kt, int lane){
    int row = 16*rt + (lane & 15);
    int k0  = 32*kt + 8*(lane >> 4);
    const float4* p = (const float4*)(W + row*EE + k0);
    float4 a = p[0], b = p[1];
    bf16x8 r;
    r[0]=(short)bf16_(a.x); r[1]=(short)bf16_(a.y); r[2]=(short)bf16_(a.z); r[3]=(short)bf16_(a.w);
    r[4]=(short)bf16_(b.x); r[5]=(short)bf16_(b.y); r[6]=(short)bf16_(b.z); r[7]=(short)bf16_(b.w);
    return r;
}

// h_lds: bf16 [col b][k], 16 rows x 128, XOR-swizzled in 16B chunks:
// element (b,k) lives at b*128 + ((k>>3 ^ b)<<3) + (k&7). Makes the
// B-frag ds_read_b128 (16 lanes same chunk-range, different b) conflict-free.

template <int IS_DEC>
__global__ __attribute__((amdgpu_flat_work_group_size(1024,1024)))
void lstm_mfma(const float* __restrict__ x,
               const float* __restrict__ Wg_all,
               const float* __restrict__ wi_all,
               const float* __restrict__ b_all,
               const float* __restrict__ lw_all,
               const float* __restrict__ lb_all,
               float* __restrict__ ws_h,
               float* __restrict__ ws_c,
               float* __restrict__ out)
{
    const int t    = threadIdx.x;   // 1024 threads = 16 waves
    const int w    = t >> 6;
    const int lane = t & 63;
    const int q    = lane >> 4;
    const int c    = lane & 15;     // output column = batch slot
    const bool upper = (w >= 8);    // waves 8-15: f,o gates + state owner
    const int e0 = (upper ? 16*(w-8) : 16*w) + 4*q;  // e-range base (4 elems)

    __shared__ unsigned short h_lds[16*EE];  // 4 KB, swizzled
    __shared__ float p_lds[16*132];          // i*g products, padded stride
    __shared__ float x_lds[TT*16];           // inputs [step][col]
    __shared__ float psum_lds[128];
    __shared__ float u0_lds[16];
    __shared__ int   id_lds[BB];
    __shared__ int   blist[16];
    __shared__ int   nslots_s;
    __shared__ float bl_sh;

    int myid = 0, nslots = 16;
    if (IS_DEC){
        myid = blockIdx.x / NCHUNK;
        int chunk = blockIdx.x % NCHUNK;
        for (int j = t; j < BB; j += 1024) id_lds[j] = (int)x[j*XROW + TT];
        if (t < 16) blist[t] = 0;
        __syncthreads();
        if (t < BB && id_lds[t] == myid){
            int r = 0;
            for (int j = 0; j < t; ++j) r += (id_lds[j] == myid) ? 1 : 0;
            int slot = r - chunk*16;
            if (slot >= 0 && slot < 16) blist[slot] = t;
        }
        if (t == 0){
            int cnt = 0;
            for (int j = 0; j < BB; ++j) cnt += (id_lds[j] == myid) ? 1 : 0;
            int ns = cnt - chunk*16;
            nslots_s = ns < 0 ? 0 : (ns > 16 ? 16 : ns);
            bl_sh = lb_all[myid];
        }
        __syncthreads();
        nslots = nslots_s;
        if (nslots == 0) return;    // uniform exit, no barriers after
    }
    const int gb = IS_DEC ? blist[c] : (blockIdx.x*16 + c);

    // input preload: x_lds[s][cc]
    for (int j = t; j < TT*16; j += 1024){
        int s = j >> 4, cc = j & 15;
        int gbl = IS_DEC ? blist[cc] : (blockIdx.x*16 + cc);
        x_lds[j] = x[gbl*XROW + s];
    }

    const float* Wb  = Wg_all + (IS_DEC ? myid*GG*EE : 0);
    const float* wib = wi_all + (IS_DEC ? myid*GG : 0);
    const float* bbb = b_all  + (IS_DEC ? myid*GG : 0);

    // weights: wave w owns row-tiles w (i/f) and w+16 (g/o) -> 40 VGPRs bf16
    const int rt_a = w, rt_b = w + 16;
    bf16x8 wA[4], wB[4];
    #pragma unroll
    for (int kt = 0; kt < 4; ++kt){
        wA[kt] = load_afrag(Wb, rt_a, kt, lane);
        wB[kt] = load_afrag(Wb, rt_b, kt, lane);
    }
    // 5th K-tile A-frags: k_local 0 = bias, 1 = wi (lanes q==0), else 0
    bf16x8 wA4 = {0,0,0,0,0,0,0,0}, wB4 = {0,0,0,0,0,0,0,0};
    if (q == 0){
        int rowa = 16*rt_a + c, rowb = 16*rt_b + c;
        wA4[0] = (short)bf16_(bbb[rowa]); wA4[1] = (short)bf16_(wib[rowa]);
        wB4[0] = (short)bf16_(bbb[rowb]); wB4[1] = (short)bf16_(wib[rowb]);
    }

    float4 cst = {0,0,0,0};
    float4 wl4 = {0,0,0,0};
    float4 hreg = {0,0,0,0};

    if (!IS_DEC){
        for (int j = t; j < 16*EE/2; j += 1024) ((unsigned*)h_lds)[j] = 0u;
    } else if (upper){
        float4 hv = *(const float4*)&ws_h[gb*EE + e0];
        cst       = *(const float4*)&ws_c[gb*EE + e0];
        wl4       = *(const float4*)&lw_all[myid*EE + e0];
        unsigned lo = (unsigned)bf16_(hv.x) | ((unsigned)bf16_(hv.y) << 16);
        unsigned hi = (unsigned)bf16_(hv.z) | ((unsigned)bf16_(hv.w) << 16);
        int ch = e0 >> 3, off = e0 & 7;
        *(uint2*)&h_lds[c*EE + ((ch ^ c) << 3) + off] = make_uint2(lo, hi);
        float ps = hv.x*wl4.x + hv.y*wl4.y + hv.z*wl4.z + hv.w*wl4.w;
        ps += __shfl_xor(ps, 16);
        ps += __shfl_xor(ps, 32);
        if (lane < 16) psum_lds[(w-8)*16 + lane] = ps;
    }
    __syncthreads();
    if (IS_DEC && t < 16){
        float s8 = 0;
        #pragma unroll
        for (int j = 0; j < 8; ++j) s8 += psum_lds[j*16 + t];
        u0_lds[t] = s8 + bl_sh;     // u0
    }
    __syncthreads();

    for (int s = 0; s < TT; ++s){
        float uval;
        if (IS_DEC) uval = (s == 0) ? u0_lds[c] : x_lds[(TT - s)*16 + c];
        else        uval = x_lds[s*16 + c];

        f32x4 accA = {0,0,0,0}, accB = {0,0,0,0};
        #pragma unroll
        for (int kt = 0; kt < 4; ++kt){
            int idx = c*EE + (((4*kt + q) ^ c) << 3);
            bf16x8 bf = *(const bf16x8*)&h_lds[idx];
            accA = __builtin_amdgcn_mfma_f32_16x16x32_bf16(wA[kt], bf, accA, 0, 0, 0);
            accB = __builtin_amdgcn_mfma_f32_16x16x32_bf16(wB[kt], bf, accB, 0, 0, 0);
        }
        {   // 5th K-tile: H_ext = [1, u, 0...] -> adds bias + u*wi
            bf16x8 b4 = {0,0,0,0,0,0,0,0};
            if (q == 0){ b4[0] = (short)0x3F80; b4[1] = (short)bf16_(uval); }
            accA = __builtin_amdgcn_mfma_f32_16x16x32_bf16(wA4, b4, accA, 0, 0, 0);
            accB = __builtin_amdgcn_mfma_f32_16x16x32_bf16(wB4, b4, accB, 0, 0, 0);
        }

        if (!upper){   // waves 0-7: i,g -> P = sigmoid(i)*tanh(g)
            float4 P;
            P.x = sig_(accA[0]) * tanh2_(accB[0]);
            P.y = sig_(accA[1]) * tanh2_(accB[1]);
            P.z = sig_(accA[2]) * tanh2_(accB[2]);
            P.w = sig_(accA[3]) * tanh2_(accB[3]);
            *(float4*)&p_lds[c*132 + e0] = P;
        }
        __syncthreads();   // B1: P ready
        if (upper){        // waves 8-15: f,o + state update
            float4 P = *(const float4*)&p_lds[c*132 + e0];
            cst.x = fmaf(sig_(accA[0]), cst.x, P.x);
            cst.y = fmaf(sig_(accA[1]), cst.y, P.y);
            cst.z = fmaf(sig_(accA[2]), cst.z, P.z);
            cst.w = fmaf(sig_(accA[3]), cst.w, P.w);
            hreg.x = sig_(accB[0]) * tanh2_(cst.x);
            hreg.y = sig_(accB[1]) * tanh2_(cst.y);
            hreg.z = sig_(accB[2]) * tanh2_(cst.z);
            hreg.w = sig_(accB[3]) * tanh2_(cst.w);
            unsigned lo = (unsigned)bf16_(hreg.x) | ((unsigned)bf16_(hreg.y) << 16);
            unsigned hi = (unsigned)bf16_(hreg.z) | ((unsigned)bf16_(hreg.w) << 16);
            int ch = e0 >> 3, off = e0 & 7;
            *(uint2*)&h_lds[c*EE + ((ch ^ c) << 3) + off] = make_uint2(lo, hi);
            if (IS_DEC){
                float ps = hreg.x*wl4.x + hreg.y*wl4.y + hreg.z*wl4.z + hreg.w*wl4.w;
                ps += __shfl_xor(ps, 16);
                ps += __shfl_xor(ps, 32);
                if (lane < 16) psum_lds[(w-8)*16 + lane] = ps;
            }
        }
        __syncthreads();   // B2: h_lds + psums ready
        if (IS_DEC && t < nslots){   // wave 0 reduces output; hidden under next MFMA
            float s8 = 0;
            #pragma unroll
            for (int j = 0; j < 8; ++j) s8 += psum_lds[j*16 + t];
            out[blist[t]*TT + (TT - 1 - s)] = s8 + bl_sh;
        }
    }

    if (!IS_DEC && upper){   // hand off exact f32 h,c to decoder
        *(float4*)&ws_h[gb*EE + e0] = hreg;
        *(float4*)&ws_c[gb*EE + e0] = cst;
    }
}

extern "C" void kernel_launch(void* const* d_in, const int* in_sizes, int n_in,
                              void* d_out, int out_size, void* d_ws, size_t ws_size,
                              hipStream_t stream) {
    const float* x       = (const float*)d_in[0];
    const float* enc_wih = (const float*)d_in[1];
    const float* enc_whh = (const float*)d_in[2];
    const float* enc_b   = (const float*)d_in[3];
    const float* dec_wih = (const float*)d_in[4];
    const float* dec_whh = (const float*)d_in[5];
    const float* dec_b   = (const float*)d_in[6];
    const float* lin_w   = (const float*)d_in[7];
    const float* lin_b   = (const float*)d_in[8];
    float* out  = (float*)d_out;
    float* wsf  = (float*)d_ws;
    float* ws_h = wsf;
    float* ws_c = wsf + BB*EE;   // 512 KB total

    hipLaunchKernelGGL((lstm_mfma<0>), dim3(BB/16), dim3(1024), 0, stream,
                       x, enc_whh, enc_wih, enc_b, lin_w, lin_b, ws_h, ws_c, out);
    hipLaunchKernelGGL((lstm_mfma<1>), dim3(16*NCHUNK), dim3(1024), 0, stream,
                       x, dec_whh, dec_wih, dec_b, lin_w, lin_b, ws_h, ws_c, out);
}